// Round 5
// baseline (781.707 us; speedup 1.0000x reference)
//
#include <hip/hip_runtime.h>
#include <hip/hip_bf16.h>
#include <math.h>

#define S 128
#define N 512
#define P 92
#define DIN 604    // P + N
#define KC0 19     // ceil(DIN/32)
#define D 128
#define KC1 4      // D/32
#define HID 256
#define MAXDEG 64

typedef unsigned short ushort_t;
typedef __attribute__((ext_vector_type(8))) short frag8;     // 8 bf16
typedef __attribute__((ext_vector_type(4))) float floatx4;   // 4 fp32 acc

__device__ inline void split1(float x, unsigned short& h, unsigned short& l) {
    __hip_bfloat16 hb = __float2bfloat16(x);
    float hf = __bfloat162float(hb);
    __hip_bfloat16 lb = __float2bfloat16(x - hf);
    h = *(unsigned short*)&hb;
    l = *(unsigned short*)&lb;
}

// ---------------- pre-pass over conn: padded CSR + dinv + zero pooled ----------------
// int4 reads (16 B/lane). CSR rows padded to multiple of 8 with self-index;
// degs[row] = padded | (padcount << 16).
__global__ void k_pre(const int* __restrict__ conn,
                      unsigned short* __restrict__ idx,
                      int* __restrict__ degs,
                      float* __restrict__ dinv,
                      float* __restrict__ pooled) {
    int zidx = blockIdx.x * 256 + (int)threadIdx.x;
    if (zidx < S * D) pooled[zidx] = 0.f;

    int row  = blockIdx.x * 4 + (threadIdx.x >> 6);
    int lane = threadIdx.x & 63;
    const int4* r = (const int4*)(conn + (size_t)row * N);
    unsigned short* irow = idx + (size_t)row * MAXDEG;
    int deg = 0;
#pragma unroll
    for (int it = 0; it < 2; ++it) {
        int4 c = r[it * 64 + lane];
        int col0 = it * 256 + lane * 4;
#pragma unroll
        for (int comp = 0; comp < 4; ++comp) {
            int cv = (comp == 0) ? c.x : (comp == 1) ? c.y : (comp == 2) ? c.z : c.w;
            unsigned long long bits = __ballot(cv != 0);
            int below = __popcll(bits & ((1ull << lane) - 1ull));
            if (cv != 0) {
                int pos = deg + below;
                if (pos < MAXDEG) irow[pos] = (unsigned short)(col0 + comp);
            }
            deg += __popcll(bits);
        }
    }
    if (lane == 0) {
        float dv = rsqrtf((float)(deg + 1));
        if (deg > MAXDEG) deg = MAXDEG;
        int padded = (deg + 7) & ~7;
        for (int p = deg; p < padded; ++p) irow[p] = (unsigned short)(row & (N - 1));
        degs[row] = padded | ((padded - deg) << 16);
        dinv[row] = dv;
    }
}

// ---------------- weight transform: W[K][128] -> fragment-major bf16 hi/lo ----------------
// layout: [kc][ctile 0..7][lane 0..63][j 0..7], elem = W[kc*32 + (lane>>4)*8 + j][16*ctile + (lane&15)]
__global__ void k_wt(const float* __restrict__ W, int K, int KC,
                     unsigned short* __restrict__ th, unsigned short* __restrict__ tl) {
    int t = blockIdx.x * 256 + (int)threadIdx.x;       // over KC*512
    if (t >= KC * 512) return;
    int lane = t & 63, c = (t >> 6) & 7, kc = t >> 9;
    int lr = lane & 15, q = lane >> 4;
    int n = 16 * c + lr;
    ushort4 h0, h1, l0, l1;
    unsigned short hh[8], ll[8];
#pragma unroll
    for (int j = 0; j < 8; ++j) {
        int k = kc * 32 + q * 8 + j;
        float v = (k < K) ? W[(size_t)k * 128 + n] : 0.f;
        split1(v, hh[j], ll[j]);
    }
    h0 = make_ushort4(hh[0], hh[1], hh[2], hh[3]);
    h1 = make_ushort4(hh[4], hh[5], hh[6], hh[7]);
    l0 = make_ushort4(ll[0], ll[1], ll[2], ll[3]);
    l1 = make_ushort4(ll[4], ll[5], ll[6], ll[7]);
    *(ushort4*)(th + (size_t)t * 8)     = h0;
    *(ushort4*)(th + (size_t)t * 8 + 4) = h1;
    *(ushort4*)(tl + (size_t)t * 8)     = l0;
    *(ushort4*)(tl + (size_t)t * 8 + 4) = l1;
}

// ---------------- layer-0: y = dinv .* ([nf|bf] @ W0), split-bf16 MFMA, pipelined ----------------
__global__ __launch_bounds__(128) void k_y0_mfma(
    const float* __restrict__ nf, const float* __restrict__ bfm,
    const unsigned short* __restrict__ w0fh, const unsigned short* __restrict__ w0fl,
    const float* __restrict__ dinv, float* __restrict__ y)
{
    __shared__ __align__(16) unsigned short AsH[64][40], AsL[64][40];  // 80 B pitch
    __shared__ __align__(16) unsigned short BsH[4096], BsL[4096];      // fragment-major
    int s  = blockIdx.y;
    int m0 = blockIdx.x * 64;
    int tid = threadIdx.x, lane = tid & 63, w = tid >> 6;
    int lr = lane & 15, q = lane >> 4;
    const float* nfs = nf  + (size_t)s * N * P;
    const float* bfs = bfm + (size_t)s * N * N;

    floatx4 acc[2][8];
#pragma unroll
    for (int r = 0; r < 2; ++r)
#pragma unroll
        for (int c = 0; c < 8; ++c)
            acc[r][c] = (floatx4){0.f, 0.f, 0.f, 0.f};

    float4 pa[2][4];
    uint4 pbh[4], pbl[4];

#define LOAD_A(kc, dst)                                                      \
    {                                                                        \
        int k0_ = (kc) * 32;                                                 \
        _Pragma("unroll")                                                    \
        for (int l = 0; l < 4; ++l) {                                        \
            int i2 = tid + l * 128;                                          \
            int row = i2 >> 3, q4 = i2 & 7;                                  \
            int k = k0_ + q4 * 4, m = m0 + row;                              \
            float4 v = make_float4(0.f, 0.f, 0.f, 0.f);                      \
            if (k < P)        v = *(const float4*)(nfs + (size_t)m * P + k); \
            else if (k < DIN) v = *(const float4*)(bfs + (size_t)m * N + (k - P)); \
            (dst)[l] = v;                                                    \
        }                                                                    \
    }
#define LOAD_B(kc)                                                           \
    {                                                                        \
        const unsigned short* bh_ = w0fh + (size_t)(kc) * 4096;              \
        const unsigned short* bl_ = w0fl + (size_t)(kc) * 4096;              \
        _Pragma("unroll")                                                    \
        for (int l = 0; l < 4; ++l) {                                        \
            pbh[l] = *(const uint4*)(bh_ + (size_t)(tid + l * 128) * 8);     \
            pbl[l] = *(const uint4*)(bl_ + (size_t)(tid + l * 128) * 8);     \
        }                                                                    \
    }

    LOAD_A(0, pa[0]);
    LOAD_B(0);
    LOAD_A(1, pa[1]);

    for (int kc = 0; kc < KC0; ++kc) {
        int cur = kc & 1;
#pragma unroll
        for (int l = 0; l < 4; ++l) {
            int i2 = tid + l * 128;
            int row = i2 >> 3, q4 = i2 & 7;
            float4 v = pa[cur][l];
            ushort4 h, lo;
            split1(v.x, h.x, lo.x); split1(v.y, h.y, lo.y);
            split1(v.z, h.z, lo.z); split1(v.w, h.w, lo.w);
            *(ushort4*)&AsH[row][q4 * 4] = h;
            *(ushort4*)&AsL[row][q4 * 4] = lo;
            *(uint4*)&BsH[(size_t)i2 * 8] = pbh[l];
            *(uint4*)&BsL[(size_t)i2 * 8] = pbl[l];
        }
        __syncthreads();
        if (kc + 1 < KC0) LOAD_B(kc + 1);
        if (kc + 2 < KC0) LOAD_A(kc + 2, pa[cur]);

        frag8 a_h[2], a_l[2];
        a_h[0] = *(const frag8*)&AsH[32 * w + lr][q * 8];
        a_h[1] = *(const frag8*)&AsH[32 * w + 16 + lr][q * 8];
        a_l[0] = *(const frag8*)&AsL[32 * w + lr][q * 8];
        a_l[1] = *(const frag8*)&AsL[32 * w + 16 + lr][q * 8];
#pragma unroll
        for (int c = 0; c < 8; ++c) {
            frag8 b_h = *(const frag8*)&BsH[(c * 64 + lane) * 8];
            frag8 b_l = *(const frag8*)&BsL[(c * 64 + lane) * 8];
#pragma unroll
            for (int r = 0; r < 2; ++r) {
                acc[r][c] = __builtin_amdgcn_mfma_f32_16x16x32_bf16(a_h[r], b_h, acc[r][c], 0, 0, 0);
                acc[r][c] = __builtin_amdgcn_mfma_f32_16x16x32_bf16(a_l[r], b_h, acc[r][c], 0, 0, 0);
                acc[r][c] = __builtin_amdgcn_mfma_f32_16x16x32_bf16(a_h[r], b_l, acc[r][c], 0, 0, 0);
            }
        }
        __syncthreads();
    }
#undef LOAD_A
#undef LOAD_B
#pragma unroll
    for (int r = 0; r < 2; ++r) {
        int mb = m0 + 32 * w + 16 * r + 4 * q;
#pragma unroll
        for (int reg = 0; reg < 4; ++reg) {
            int m = mb + reg;
            float dv = dinv[s * N + m];
            float* yr = y + ((size_t)s * N + m) * D;
#pragma unroll
            for (int c = 0; c < 8; ++c)
                yr[16 * c + lr] = acc[r][c][reg] * dv;
        }
    }
}

// ---------------- layers 1,2: y = dinv .* (z @ W), split-bf16 MFMA, pipelined ----------------
__global__ __launch_bounds__(128) void k_xw_mfma(
    const float* __restrict__ zin,
    const unsigned short* __restrict__ wfh, const unsigned short* __restrict__ wfl,
    const float* __restrict__ dinv, float* __restrict__ y)
{
    __shared__ __align__(16) unsigned short AsH[64][40], AsL[64][40];
    __shared__ __align__(16) unsigned short BsH[4096], BsL[4096];
    int m0 = blockIdx.x * 64;
    int tid = threadIdx.x, lane = tid & 63, w = tid >> 6;
    int lr = lane & 15, q = lane >> 4;

    floatx4 acc[2][8];
#pragma unroll
    for (int r = 0; r < 2; ++r)
#pragma unroll
        for (int c = 0; c < 8; ++c)
            acc[r][c] = (floatx4){0.f, 0.f, 0.f, 0.f};

    float4 pa[2][4];
    uint4 pbh[4], pbl[4];

#define LOAD_A(kc, dst)                                                      \
    {                                                                        \
        int k0_ = (kc) * 32;                                                 \
        _Pragma("unroll")                                                    \
        for (int l = 0; l < 4; ++l) {                                        \
            int i2 = tid + l * 128;                                          \
            int row = i2 >> 3, q4 = i2 & 7;                                  \
            (dst)[l] = *(const float4*)(zin + (size_t)(m0 + row) * D + k0_ + q4 * 4); \
        }                                                                    \
    }
#define LOAD_B(kc)                                                           \
    {                                                                        \
        const unsigned short* bh_ = wfh + (size_t)(kc) * 4096;               \
        const unsigned short* bl_ = wfl + (size_t)(kc) * 4096;               \
        _Pragma("unroll")                                                    \
        for (int l = 0; l < 4; ++l) {                                        \
            pbh[l] = *(const uint4*)(bh_ + (size_t)(tid + l * 128) * 8);     \
            pbl[l] = *(const uint4*)(bl_ + (size_t)(tid + l * 128) * 8);     \
        }                                                                    \
    }

    LOAD_A(0, pa[0]);
    LOAD_B(0);
    LOAD_A(1, pa[1]);

    for (int kc = 0; kc < KC1; ++kc) {
        int cur = kc & 1;
#pragma unroll
        for (int l = 0; l < 4; ++l) {
            int i2 = tid + l * 128;
            int row = i2 >> 3, q4 = i2 & 7;
            float4 v = pa[cur][l];
            ushort4 h, lo;
            split1(v.x, h.x, lo.x); split1(v.y, h.y, lo.y);
            split1(v.z, h.z, lo.z); split1(v.w, h.w, lo.w);
            *(ushort4*)&AsH[row][q4 * 4] = h;
            *(ushort4*)&AsL[row][q4 * 4] = lo;
            *(uint4*)&BsH[(size_t)i2 * 8] = pbh[l];
            *(uint4*)&BsL[(size_t)i2 * 8] = pbl[l];
        }
        __syncthreads();
        if (kc + 1 < KC1) LOAD_B(kc + 1);
        if (kc + 2 < KC1) LOAD_A(kc + 2, pa[cur]);

        frag8 a_h[2], a_l[2];
        a_h[0] = *(const frag8*)&AsH[32 * w + lr][q * 8];
        a_h[1] = *(const frag8*)&AsH[32 * w + 16 + lr][q * 8];
        a_l[0] = *(const frag8*)&AsL[32 * w + lr][q * 8];
        a_l[1] = *(const frag8*)&AsL[32 * w + 16 + lr][q * 8];
#pragma unroll
        for (int c = 0; c < 8; ++c) {
            frag8 b_h = *(const frag8*)&BsH[(c * 64 + lane) * 8];
            frag8 b_l = *(const frag8*)&BsL[(c * 64 + lane) * 8];
#pragma unroll
            for (int r = 0; r < 2; ++r) {
                acc[r][c] = __builtin_amdgcn_mfma_f32_16x16x32_bf16(a_h[r], b_h, acc[r][c], 0, 0, 0);
                acc[r][c] = __builtin_amdgcn_mfma_f32_16x16x32_bf16(a_l[r], b_h, acc[r][c], 0, 0, 0);
                acc[r][c] = __builtin_amdgcn_mfma_f32_16x16x32_bf16(a_h[r], b_l, acc[r][c], 0, 0, 0);
            }
        }
        __syncthreads();
    }
#undef LOAD_A
#undef LOAD_B
#pragma unroll
    for (int r = 0; r < 2; ++r) {
        int mb = m0 + 32 * w + 16 * r + 4 * q;
#pragma unroll
        for (int reg = 0; reg < 4; ++reg) {
            int m = mb + reg;
            float dv = dinv[m];
            float* yr = y + (size_t)m * D;
#pragma unroll
            for (int c = 0; c < 8; ++c)
                yr[16 * c + lr] = acc[r][c][reg] * dv;
        }
    }
}

// ---------------- sparse propagate via padded CSR, exact 8-deep batches ----------------
__global__ __launch_bounds__(256) void k_prop_csr(
    const unsigned short* __restrict__ idx, const int* __restrict__ degs,
    const float* __restrict__ dinv,
    const float* __restrict__ yin, const float* __restrict__ bias,
    float* __restrict__ z, float* __restrict__ pooled)
{
    __shared__ unsigned short sidx[8][MAXDEG];
    __shared__ int sdeg[8];
    int s  = blockIdx.y;
    int g  = threadIdx.x >> 5;
    int j  = blockIdx.x * 8 + g;
    int f4 = threadIdx.x & 31;
    const float* ys = yin + (size_t)s * N * D;

    {
        int tg = threadIdx.x >> 5, pair = threadIdx.x & 31;
        const unsigned int* src = (const unsigned int*)(idx + ((size_t)(s * N + blockIdx.x * 8 + tg)) * MAXDEG);
        ((unsigned int*)&sidx[tg][0])[pair] = src[pair];
        if (threadIdx.x < 8) sdeg[threadIdx.x] = degs[s * N + blockIdx.x * 8 + threadIdx.x];
    }
    __syncthreads();

    float4 yj = *(const float4*)(ys + (size_t)j * D + f4 * 4);
    float4 acc = yj;                      // +I self loop
    int dp = sdeg[g];
    int d = dp & 0xffff, pads = dp >> 16;
    for (int b = 0; b < d; b += 8) {
        float4 v[8];
#pragma unroll
        for (int qq = 0; qq < 8; ++qq) {
            int i = sidx[g][b + qq];
            v[qq] = *(const float4*)(ys + (size_t)i * D + f4 * 4);
        }
#pragma unroll
        for (int qq = 0; qq < 8; ++qq) {
            acc.x += v[qq].x; acc.y += v[qq].y; acc.z += v[qq].z; acc.w += v[qq].w;
        }
    }
    float fp = (float)pads;
    acc.x -= fp * yj.x; acc.y -= fp * yj.y; acc.z -= fp * yj.z; acc.w -= fp * yj.w;

    float dv = dinv[s * N + j];
    int f = f4 * 4;
    float4 r = { acc.x * dv + bias[f],     acc.y * dv + bias[f + 1],
                 acc.z * dv + bias[f + 2], acc.w * dv + bias[f + 3] };

    if (pooled == nullptr) {
        *(float4*)(z + ((size_t)s * N + j) * D + f) = r;
    } else {
        __shared__ float red[8][D];
        *(float4*)&red[g][f] = r;
        __syncthreads();
        if (threadIdx.x < D) {
            float t = 0.f;
#pragma unroll
            for (int qq = 0; qq < 8; ++qq) t += red[qq][threadIdx.x];
            atomicAdd(pooled + s * D + threadIdx.x, t);
        }
    }
}

// ---------------- softplus + MLP head ----------------
__global__ __launch_bounds__(256) void k_head(
    const float* __restrict__ pooled,
    const float* __restrict__ Wh, const float* __restrict__ bh,
    const float* __restrict__ Wi, const float* __restrict__ bi,
    const float* __restrict__ We, const float* __restrict__ be,
    const float* __restrict__ Wlb, const float* __restrict__ blb,
    const float* __restrict__ Wub, const float* __restrict__ bub,
    float* __restrict__ out)
{
    int s = blockIdx.x;
    int t = threadIdx.x;
    __shared__ float sp[D];
    __shared__ float h[HID];
    if (t < D) {
        float x = pooled[s * D + t];
        sp[t] = (x > 20.f) ? x : log1pf(expf(x));
    }
    __syncthreads();
    {
        float a = bh[t];
        for (int g = 0; g < D; ++g)
            a += sp[g] * Wh[g * HID + t];
        h[t] = a;
    }
    __syncthreads();
    if (t < 100) {
        float a = bi[t];
        for (int k = 0; k < HID; ++k)
            a += h[k] * Wi[k * 100 + t];
        out[s * 100 + t] = a;
    } else if (t < 103) {
        const float* Wv = (t == 100) ? We : (t == 101) ? Wlb : Wub;
        float bv = (t == 100) ? be[0] : (t == 101) ? blb[0] : bub[0];
        float a = bv;
        for (int k = 0; k < HID; ++k)
            a += h[k] * Wv[k];
        out[S * 100 + (t - 100) * S + s] = a;
    }
}

extern "C" void kernel_launch(void* const* d_in, const int* in_sizes, int n_in,
                              void* d_out, int out_size, void* d_ws, size_t ws_size,
                              hipStream_t stream) {
    const float* nf   = (const float*)d_in[0];
    const float* bfm  = (const float*)d_in[1];
    const int*   conn = (const int*)d_in[2];
    const float* W0 = (const float*)d_in[4];
    const float* b0 = (const float*)d_in[5];
    const float* W1 = (const float*)d_in[6];
    const float* b1 = (const float*)d_in[7];
    const float* W2 = (const float*)d_in[8];
    const float* b2 = (const float*)d_in[9];
    const float* Wh = (const float*)d_in[10];
    const float* bh = (const float*)d_in[11];
    const float* Wi = (const float*)d_in[12];
    const float* bi = (const float*)d_in[13];
    const float* We = (const float*)d_in[14];
    const float* be = (const float*)d_in[15];
    const float* Wlb = (const float*)d_in[16];
    const float* blb = (const float*)d_in[17];
    const float* Wub = (const float*)d_in[18];
    const float* bub = (const float*)d_in[19];
    float* out = (float*)d_out;

    char* ws = (char*)d_ws;
    float* ybuf = (float*)ws;                                   // 32 MB
    float* zbuf = (float*)(ws + (1u << 25));                    // 32 MB
    char* base2 = ws + (1u << 26);
    float* dinv = (float*)(base2);                              // 256 KB
    int*   degs = (int*)(base2 + 0x40000);                      // 256 KB
    float* pooled = (float*)(base2 + 0x80000);                  // 64 KB
    unsigned short* idx = (unsigned short*)(base2 + 0x90000);   // 8 MB
    unsigned short* w0fh = (unsigned short*)(base2 + 0x890000); // 152 KB (pad 192K)
    unsigned short* w0fl = (unsigned short*)(base2 + 0x8C0000);
    unsigned short* w1fh = (unsigned short*)(base2 + 0x8F0000); // 32 KB (pad 64K)
    unsigned short* w1fl = (unsigned short*)(base2 + 0x900000);
    unsigned short* w2fh = (unsigned short*)(base2 + 0x910000);
    unsigned short* w2fl = (unsigned short*)(base2 + 0x920000);

    k_pre<<<S * N / 4, 256, 0, stream>>>(conn, idx, degs, dinv, pooled);
    k_wt<<<(KC0 * 512 + 255) / 256, 256, 0, stream>>>(W0, DIN, KC0, w0fh, w0fl);
    k_wt<<<(KC1 * 512 + 255) / 256, 256, 0, stream>>>(W1, D, KC1, w1fh, w1fl);
    k_wt<<<(KC1 * 512 + 255) / 256, 256, 0, stream>>>(W2, D, KC1, w2fh, w2fl);

    k_y0_mfma<<<dim3(N / 64, S), 128, 0, stream>>>(nf, bfm, w0fh, w0fl, dinv, ybuf);
    k_prop_csr<<<dim3(N / 8, S), 256, 0, stream>>>(idx, degs, dinv, ybuf, b0, zbuf, nullptr);
    k_xw_mfma<<<S * N / 64, 128, 0, stream>>>(zbuf, w1fh, w1fl, dinv, ybuf);
    k_prop_csr<<<dim3(N / 8, S), 256, 0, stream>>>(idx, degs, dinv, ybuf, b1, zbuf, nullptr);
    k_xw_mfma<<<S * N / 64, 128, 0, stream>>>(zbuf, w2fh, w2fl, dinv, ybuf);
    k_prop_csr<<<dim3(N / 8, S), 256, 0, stream>>>(idx, degs, dinv, ybuf, b2, zbuf, pooled);
    k_head<<<S, 256, 0, stream>>>(pooled, Wh, bh, Wi, bi, We, be, Wlb, blb, Wub, bub, out);
}

// Round 6
// 589.609 us; speedup vs baseline: 1.3258x; 1.3258x over previous
//
#include <hip/hip_runtime.h>
#include <hip/hip_bf16.h>
#include <math.h>

#define S 128
#define N 512
#define P 92
#define DIN 604   // P + N
#define KPAD0 608 // DIN padded to 32
#define D 128
#define HID 256
#define MAXDEG 64

typedef __attribute__((ext_vector_type(8))) short frag8;     // 8 bf16
typedef __attribute__((ext_vector_type(4))) float floatx4;   // 4 fp32 acc

__device__ inline void split1(float x, unsigned short& h, unsigned short& l) {
    __hip_bfloat16 hb = __float2bfloat16(x);
    float hf = __bfloat162float(hb);
    __hip_bfloat16 lb = __float2bfloat16(x - hf);
    h = *(unsigned short*)&hb;
    l = *(unsigned short*)&lb;
}

// ---------------- pre-pass over conn: padded CSR + dinv + zero pooled ----------------
// int4 reads. CSR rows padded to multiple of 8 with self-index;
// degs[row] = padded | (padcount << 16).
__global__ void k_pre(const int* __restrict__ conn,
                      unsigned short* __restrict__ idx,
                      int* __restrict__ degs,
                      float* __restrict__ dinv,
                      float* __restrict__ pooled) {
    int zidx = blockIdx.x * 256 + (int)threadIdx.x;
    if (zidx < S * D) pooled[zidx] = 0.f;

    int row  = blockIdx.x * 4 + (threadIdx.x >> 6);
    int lane = threadIdx.x & 63;
    const int4* r = (const int4*)(conn + (size_t)row * N);
    unsigned short* irow = idx + (size_t)row * MAXDEG;
    int deg = 0;
#pragma unroll
    for (int it = 0; it < 2; ++it) {
        int4 c = r[it * 64 + lane];
        int col0 = it * 256 + lane * 4;
#pragma unroll
        for (int comp = 0; comp < 4; ++comp) {
            int cv = (comp == 0) ? c.x : (comp == 1) ? c.y : (comp == 2) ? c.z : c.w;
            unsigned long long bits = __ballot(cv != 0);
            int below = __popcll(bits & ((1ull << lane) - 1ull));
            if (cv != 0) {
                int pos = deg + below;
                if (pos < MAXDEG) irow[pos] = (unsigned short)(col0 + comp);
            }
            deg += __popcll(bits);
        }
    }
    if (lane == 0) {
        float dv = rsqrtf((float)(deg + 1));
        if (deg > MAXDEG) deg = MAXDEG;
        int padded = (deg + 7) & ~7;
        for (int p = deg; p < padded; ++p) irow[p] = (unsigned short)(row & (N - 1));
        degs[row] = padded | ((padded - deg) << 16);
        dinv[row] = dv;
    }
}

// ---------------- weight transform: W[K][128] -> Wt_hi/lo[n][Kpad] bf16 ----------------
__global__ void k_wt(const float* __restrict__ W, int K, int Kpad,
                     unsigned short* __restrict__ th, unsigned short* __restrict__ tl) {
    int i = blockIdx.x * 256 + threadIdx.x;           // over Kpad*128
    if (i >= Kpad * 128) return;
    int k = i >> 7, n = i & 127;
    float v = (k < K) ? W[(size_t)k * 128 + n] : 0.f;
    unsigned short h, l;
    split1(v, h, l);
    th[(size_t)n * Kpad + k] = h;
    tl[(size_t)n * Kpad + k] = l;
}

// ---------------- layer-0: y = dinv .* ([nf|bf] @ W0), split-bf16 MFMA (r4 form) ----------------
__global__ __launch_bounds__(128) void k_y0_mfma(
    const float* __restrict__ nf, const float* __restrict__ bfm,
    const unsigned short* __restrict__ w0th, const unsigned short* __restrict__ w0tl,
    const float* __restrict__ dinv, float* __restrict__ y)
{
    __shared__ __align__(16) unsigned short As_hi[64][32], As_lo[64][32];
    __shared__ __align__(16) unsigned short Bs_hi[128][32], Bs_lo[128][32];
    int s  = blockIdx.y;
    int m0 = blockIdx.x * 64;
    int tid = threadIdx.x;
    int lane = tid & 63, w = tid >> 6;
    int lr = lane & 15, q = lane >> 4;
    const float* nfs = nf  + (size_t)s * N * P;
    const float* bfs = bfm + (size_t)s * N * N;

    floatx4 acc[2][8];
#pragma unroll
    for (int r = 0; r < 2; ++r)
#pragma unroll
        for (int c = 0; c < 8; ++c)
            acc[r][c] = (floatx4){0.f, 0.f, 0.f, 0.f};

    for (int kc = 0; kc < KPAD0 / 32; ++kc) {
        int k0 = kc * 32;
#pragma unroll
        for (int l = 0; l < 4; ++l) {
            int i2 = tid + l * 128;
            int row = i2 >> 3, q4 = i2 & 7;
            int k = k0 + q4 * 4;
            int m = m0 + row;
            float4 v = make_float4(0.f, 0.f, 0.f, 0.f);
            if (k < P)        v = *(const float4*)(nfs + (size_t)m * P + k);
            else if (k < DIN) v = *(const float4*)(bfs + (size_t)m * N + (k - P));
            ushort4 h, lo;
            split1(v.x, h.x, lo.x); split1(v.y, h.y, lo.y);
            split1(v.z, h.z, lo.z); split1(v.w, h.w, lo.w);
            *(ushort4*)&As_hi[row][q4 * 4] = h;
            *(ushort4*)&As_lo[row][q4 * 4] = lo;
        }
#pragma unroll
        for (int l = 0; l < 4; ++l) {
            int i2 = tid + l * 128;
            int n = i2 >> 2, q8 = i2 & 3;
            *(uint4*)&Bs_hi[n][q8 * 8] = *(const uint4*)(w0th + (size_t)n * KPAD0 + k0 + q8 * 8);
            *(uint4*)&Bs_lo[n][q8 * 8] = *(const uint4*)(w0tl + (size_t)n * KPAD0 + k0 + q8 * 8);
        }
        __syncthreads();
        frag8 a_h[2], a_l[2];
        a_h[0] = *(const frag8*)&As_hi[32 * w + lr][q * 8];
        a_h[1] = *(const frag8*)&As_hi[32 * w + 16 + lr][q * 8];
        a_l[0] = *(const frag8*)&As_lo[32 * w + lr][q * 8];
        a_l[1] = *(const frag8*)&As_lo[32 * w + 16 + lr][q * 8];
#pragma unroll
        for (int c = 0; c < 8; ++c) {
            frag8 b_h = *(const frag8*)&Bs_hi[16 * c + lr][q * 8];
            frag8 b_l = *(const frag8*)&Bs_lo[16 * c + lr][q * 8];
#pragma unroll
            for (int r = 0; r < 2; ++r) {
                acc[r][c] = __builtin_amdgcn_mfma_f32_16x16x32_bf16(a_h[r], b_h, acc[r][c], 0, 0, 0);
                acc[r][c] = __builtin_amdgcn_mfma_f32_16x16x32_bf16(a_l[r], b_h, acc[r][c], 0, 0, 0);
                acc[r][c] = __builtin_amdgcn_mfma_f32_16x16x32_bf16(a_h[r], b_l, acc[r][c], 0, 0, 0);
            }
        }
        __syncthreads();
    }
#pragma unroll
    for (int r = 0; r < 2; ++r) {
        int mb = m0 + 32 * w + 16 * r + 4 * q;
#pragma unroll
        for (int reg = 0; reg < 4; ++reg) {
            int m = mb + reg;
            float dv = dinv[s * N + m];
            float* yr = y + ((size_t)s * N + m) * D;
#pragma unroll
            for (int c = 0; c < 8; ++c)
                yr[16 * c + lr] = acc[r][c][reg] * dv;
        }
    }
}

// ---------------- layers 1,2: y = dinv .* (z @ W), split-bf16 MFMA (r4 form) ----------------
__global__ __launch_bounds__(128) void k_xw_mfma(
    const float* __restrict__ zin,
    const unsigned short* __restrict__ wth, const unsigned short* __restrict__ wtl,
    const float* __restrict__ dinv, float* __restrict__ y)
{
    __shared__ __align__(16) unsigned short As_hi[64][32], As_lo[64][32];
    __shared__ __align__(16) unsigned short Bs_hi[128][32], Bs_lo[128][32];
    int m0 = blockIdx.x * 64;
    int tid = threadIdx.x;
    int lane = tid & 63, w = tid >> 6;
    int lr = lane & 15, q = lane >> 4;

    floatx4 acc[2][8];
#pragma unroll
    for (int r = 0; r < 2; ++r)
#pragma unroll
        for (int c = 0; c < 8; ++c)
            acc[r][c] = (floatx4){0.f, 0.f, 0.f, 0.f};

    for (int kc = 0; kc < D / 32; ++kc) {
        int k0 = kc * 32;
#pragma unroll
        for (int l = 0; l < 4; ++l) {
            int i2 = tid + l * 128;
            int row = i2 >> 3, q4 = i2 & 7;
            float4 v = *(const float4*)(zin + (size_t)(m0 + row) * D + k0 + q4 * 4);
            ushort4 h, lo;
            split1(v.x, h.x, lo.x); split1(v.y, h.y, lo.y);
            split1(v.z, h.z, lo.z); split1(v.w, h.w, lo.w);
            *(ushort4*)&As_hi[row][q4 * 4] = h;
            *(ushort4*)&As_lo[row][q4 * 4] = lo;
        }
#pragma unroll
        for (int l = 0; l < 4; ++l) {
            int i2 = tid + l * 128;
            int n = i2 >> 2, q8 = i2 & 3;
            *(uint4*)&Bs_hi[n][q8 * 8] = *(const uint4*)(wth + (size_t)n * D + k0 + q8 * 8);
            *(uint4*)&Bs_lo[n][q8 * 8] = *(const uint4*)(wtl + (size_t)n * D + k0 + q8 * 8);
        }
        __syncthreads();
        frag8 a_h[2], a_l[2];
        a_h[0] = *(const frag8*)&As_hi[32 * w + lr][q * 8];
        a_h[1] = *(const frag8*)&As_hi[32 * w + 16 + lr][q * 8];
        a_l[0] = *(const frag8*)&As_lo[32 * w + lr][q * 8];
        a_l[1] = *(const frag8*)&As_lo[32 * w + 16 + lr][q * 8];
#pragma unroll
        for (int c = 0; c < 8; ++c) {
            frag8 b_h = *(const frag8*)&Bs_hi[16 * c + lr][q * 8];
            frag8 b_l = *(const frag8*)&Bs_lo[16 * c + lr][q * 8];
#pragma unroll
            for (int r = 0; r < 2; ++r) {
                acc[r][c] = __builtin_amdgcn_mfma_f32_16x16x32_bf16(a_h[r], b_h, acc[r][c], 0, 0, 0);
                acc[r][c] = __builtin_amdgcn_mfma_f32_16x16x32_bf16(a_l[r], b_h, acc[r][c], 0, 0, 0);
                acc[r][c] = __builtin_amdgcn_mfma_f32_16x16x32_bf16(a_h[r], b_l, acc[r][c], 0, 0, 0);
            }
        }
        __syncthreads();
    }
#pragma unroll
    for (int r = 0; r < 2; ++r) {
        int mb = m0 + 32 * w + 16 * r + 4 * q;
#pragma unroll
        for (int reg = 0; reg < 4; ++reg) {
            int m = mb + reg;
            float dv = dinv[m];
            float* yr = y + (size_t)m * D;
#pragma unroll
            for (int c = 0; c < 8; ++c)
                yr[16 * c + lr] = acc[r][c][reg] * dv;
        }
    }
}

// ---------------- XCD-pinned sparse propagate ----------------
// 8 blocks per graph (64 targets each); swizzle pins all blocks of a graph to
// one XCD (round-robin heuristic: XCD = blockIdx % 8) so the graph's 256 KB
// y-slice stays L2-resident (16 graphs x 256 KB = 4 MB = one XCD L2).
__global__ __launch_bounds__(256) void k_prop_xcd(
    const unsigned short* __restrict__ idx, const int* __restrict__ degs,
    const float* __restrict__ dinv,
    const float* __restrict__ yin, const float* __restrict__ bias,
    float* __restrict__ z, float* __restrict__ pooled)
{
    __shared__ unsigned short sidx[64][MAXDEG];   // 8 KB
    __shared__ int sdeg[64];
    __shared__ float red[8][D];
    int b = blockIdx.x;
    int s   = ((b & 7) << 4) | ((b >> 3) & 15);
    int sub = (b >> 7) & 7;
    int j0 = sub * 64;
    int tid = threadIdx.x;
    const float* ys = yin + (size_t)s * N * D;

    {   // stage CSR for the 64 targets: 8 KB = 2048 u32, 8/thread
        const unsigned int* src = (const unsigned int*)(idx + ((size_t)s * N + j0) * MAXDEG);
        unsigned int* dst = (unsigned int*)&sidx[0][0];
#pragma unroll
        for (int l = 0; l < 8; ++l) dst[tid + l * 256] = src[tid + l * 256];
        if (tid < 64) sdeg[tid] = degs[s * N + j0 + tid];
    }
    __syncthreads();

    int g = tid >> 5, f4 = tid & 31, f = f4 * 4;
    float4 bias4 = *(const float4*)(bias + f);
    float4 pacc = make_float4(0.f, 0.f, 0.f, 0.f);

#pragma unroll
    for (int jj = 0; jj < 8; ++jj) {
        int jl = jj * 8 + g;
        int j = j0 + jl;
        float4 yj = *(const float4*)(ys + (size_t)j * D + f);
        float4 acc = yj;                                  // +I self loop
        int dp = sdeg[jl];
        int d = dp & 0xffff, pads = dp >> 16;
        for (int bb = 0; bb < d; bb += 8) {
            float4 v[8];
#pragma unroll
            for (int qq = 0; qq < 8; ++qq) {
                int i = sidx[jl][bb + qq];
                v[qq] = *(const float4*)(ys + (size_t)i * D + f);
            }
#pragma unroll
            for (int qq = 0; qq < 8; ++qq) {
                acc.x += v[qq].x; acc.y += v[qq].y; acc.z += v[qq].z; acc.w += v[qq].w;
            }
        }
        float fp = (float)pads;
        acc.x -= fp * yj.x; acc.y -= fp * yj.y; acc.z -= fp * yj.z; acc.w -= fp * yj.w;

        float dv = dinv[s * N + j];
        float4 r = { acc.x * dv + bias4.x, acc.y * dv + bias4.y,
                     acc.z * dv + bias4.z, acc.w * dv + bias4.w };
        if (pooled == nullptr) {
            *(float4*)(z + ((size_t)s * N + j) * D + f) = r;
        } else {
            pacc.x += r.x; pacc.y += r.y; pacc.z += r.z; pacc.w += r.w;
        }
    }

    if (pooled != nullptr) {
        *(float4*)&red[g][f] = pacc;
        __syncthreads();
        if (tid < D) {
            float t = 0.f;
#pragma unroll
            for (int qq = 0; qq < 8; ++qq) t += red[qq][tid];
            atomicAdd(pooled + s * D + tid, t);
        }
    }
}

// ---------------- softplus + MLP head ----------------
__global__ __launch_bounds__(256) void k_head(
    const float* __restrict__ pooled,
    const float* __restrict__ Wh, const float* __restrict__ bh,
    const float* __restrict__ Wi, const float* __restrict__ bi,
    const float* __restrict__ We, const float* __restrict__ be,
    const float* __restrict__ Wlb, const float* __restrict__ blb,
    const float* __restrict__ Wub, const float* __restrict__ bub,
    float* __restrict__ out)
{
    int s = blockIdx.x;
    int t = threadIdx.x;
    __shared__ float sp[D];
    __shared__ float h[HID];
    if (t < D) {
        float x = pooled[s * D + t];
        sp[t] = (x > 20.f) ? x : log1pf(expf(x));
    }
    __syncthreads();
    {
        float a = bh[t];
        for (int g = 0; g < D; ++g)
            a += sp[g] * Wh[g * HID + t];
        h[t] = a;
    }
    __syncthreads();
    if (t < 100) {
        float a = bi[t];
        for (int k = 0; k < HID; ++k)
            a += h[k] * Wi[k * 100 + t];
        out[s * 100 + t] = a;
    } else if (t < 103) {
        const float* Wv = (t == 100) ? We : (t == 101) ? Wlb : Wub;
        float bv = (t == 100) ? be[0] : (t == 101) ? blb[0] : bub[0];
        float a = bv;
        for (int k = 0; k < HID; ++k)
            a += h[k] * Wv[k];
        out[S * 100 + (t - 100) * S + s] = a;
    }
}

extern "C" void kernel_launch(void* const* d_in, const int* in_sizes, int n_in,
                              void* d_out, int out_size, void* d_ws, size_t ws_size,
                              hipStream_t stream) {
    const float* nf   = (const float*)d_in[0];
    const float* bfm  = (const float*)d_in[1];
    const int*   conn = (const int*)d_in[2];
    const float* W0 = (const float*)d_in[4];
    const float* b0 = (const float*)d_in[5];
    const float* W1 = (const float*)d_in[6];
    const float* b1 = (const float*)d_in[7];
    const float* W2 = (const float*)d_in[8];
    const float* b2 = (const float*)d_in[9];
    const float* Wh = (const float*)d_in[10];
    const float* bh = (const float*)d_in[11];
    const float* Wi = (const float*)d_in[12];
    const float* bi = (const float*)d_in[13];
    const float* We = (const float*)d_in[14];
    const float* be = (const float*)d_in[15];
    const float* Wlb = (const float*)d_in[16];
    const float* blb = (const float*)d_in[17];
    const float* Wub = (const float*)d_in[18];
    const float* bub = (const float*)d_in[19];
    float* out = (float*)d_out;

    char* ws = (char*)d_ws;
    float* ybuf = (float*)ws;                                   // 32 MB
    float* zbuf = (float*)(ws + (1u << 25));                    // 32 MB
    char* base2 = ws + (1u << 26);
    float* dinv = (float*)(base2);                              // 256 KB
    int*   degs = (int*)(base2 + 0x40000);                      // 256 KB
    float* pooled = (float*)(base2 + 0x80000);                  // 64 KB
    unsigned short* idx = (unsigned short*)(base2 + 0x90000);   // 8 MB
    unsigned short* w0th = (unsigned short*)(base2 + 0x890000); // 152 KB (pad 256K)
    unsigned short* w0tl = (unsigned short*)(base2 + 0x8D0000);
    unsigned short* w1th = (unsigned short*)(base2 + 0x910000); // 32 KB (pad 64K)
    unsigned short* w1tl = (unsigned short*)(base2 + 0x920000);
    unsigned short* w2th = (unsigned short*)(base2 + 0x930000);
    unsigned short* w2tl = (unsigned short*)(base2 + 0x940000);

    k_pre<<<S * N / 4, 256, 0, stream>>>(conn, idx, degs, dinv, pooled);
    k_wt<<<(KPAD0 * 128 + 255) / 256, 256, 0, stream>>>(W0, DIN, KPAD0, w0th, w0tl);
    k_wt<<<(D * 128 + 255) / 256, 256, 0, stream>>>(W1, D, D, w1th, w1tl);
    k_wt<<<(D * 128 + 255) / 256, 256, 0, stream>>>(W2, D, D, w2th, w2tl);

    k_y0_mfma<<<dim3(N / 64, S), 128, 0, stream>>>(nf, bfm, w0th, w0tl, dinv, ybuf);
    k_prop_xcd<<<S * 8, 256, 0, stream>>>(idx, degs, dinv, ybuf, b0, zbuf, nullptr);
    k_xw_mfma<<<S * N / 64, 128, 0, stream>>>(zbuf, w1th, w1tl, dinv, ybuf);
    k_prop_xcd<<<S * 8, 256, 0, stream>>>(idx, degs, dinv, ybuf, b1, zbuf, nullptr);
    k_xw_mfma<<<S * N / 64, 128, 0, stream>>>(zbuf, w2th, w2tl, dinv, ybuf);
    k_prop_xcd<<<S * 8, 256, 0, stream>>>(idx, degs, dinv, ybuf, b2, zbuf, pooled);
    k_head<<<S, 256, 0, stream>>>(pooled, Wh, bh, Wi, bi, We, be, Wlb, blb, Wub, bub, out);
}